// Round 1
// baseline (845.712 us; speedup 1.0000x reference)
//
#include <hip/hip_runtime.h>
#include <hip/hip_bf16.h>

// Pipeline: cast/transpose -> QKV GEMMs (bf16 MFMA) -> RoPE -> flash attention -> out GEMM.
// All bf16 MFMA 16x16x32, fp32 accumulate. Score scale 1/8 folded into q at RoPE time.

typedef unsigned short u16;
typedef short bf16x8 __attribute__((ext_vector_type(8)));
typedef float f32x4 __attribute__((ext_vector_type(4)));

__device__ __forceinline__ float bf2f(u16 u) {
    union { unsigned v; float f; } x; x.v = ((unsigned)u) << 16; return x.f;
}
__device__ __forceinline__ u16 f2bf(float f) {
    unsigned u = __float_as_uint(f);
    u += 0x7fffu + ((u >> 16) & 1u);   // round-to-nearest-even (finite inputs)
    return (u16)(u >> 16);
}

// ---------------- cast x (fp32 -> bf16), vectorized ----------------
__global__ void cast_bf16_kernel(const float* __restrict__ in, u16* __restrict__ out, size_t n4) {
    // n4 = number of float4 groups
    for (size_t i = blockIdx.x * (size_t)blockDim.x + threadIdx.x; i < n4;
         i += (size_t)gridDim.x * blockDim.x) {
        float4 v = ((const float4*)in)[i];
        ushort4 o;
        o.x = f2bf(v.x); o.y = f2bf(v.y); o.z = f2bf(v.z); o.w = f2bf(v.w);
        ((ushort4*)out)[i] = o;
    }
}

// ---------------- transpose + cast: W (K x N fp32) -> Wt (N x K bf16) ----------------
__global__ void transpose_cast_kernel(const float* __restrict__ W, u16* __restrict__ Wt,
                                      int K, int N) {
    __shared__ float tile[32][33];
    int x = blockIdx.x * 32 + threadIdx.x;   // n
    int y0 = blockIdx.y * 32 + threadIdx.y;  // k
    #pragma unroll
    for (int r = 0; r < 32; r += 8)
        tile[threadIdx.y + r][threadIdx.x] = W[(size_t)(y0 + r) * N + x];
    __syncthreads();
    int xo = blockIdx.y * 32 + threadIdx.x;   // k
    int yo0 = blockIdx.x * 32 + threadIdx.y;  // n
    #pragma unroll
    for (int r = 0; r < 32; r += 8)
        Wt[(size_t)(yo0 + r) * K + xo] = f2bf(tile[threadIdx.x][threadIdx.y + r]);
}

// ---------------- GEMM: C[m][n] = sum_k A[m][k] * Bt[n][k]  (both bf16 row-major, K contig) ----
// 128x128 block tile, BK=64, 4 waves in 2x2, each wave 64x64 via 4x4 16x16x32 MFMAs.
#define LDT 72  // padded LDS leading dim (elements); 144 B, 16B aligned

template <int OUT_BF16>
__global__ __launch_bounds__(256) void gemm_bt_kernel(const u16* __restrict__ A,
                                                      const u16* __restrict__ Bt,
                                                      void* __restrict__ C,
                                                      int M, int N, int K) {
    __shared__ __align__(16) u16 As[128 * LDT];
    __shared__ __align__(16) u16 Bs[128 * LDT];
    const int tid = threadIdx.x;
    const int m0 = blockIdx.y * 128;
    const int n0 = blockIdx.x * 128;
    const int w = tid >> 6, lane = tid & 63;
    const int quad = lane >> 4, ln = lane & 15;
    const int wr = (w >> 1) * 64, wc = (w & 1) * 64;

    f32x4 acc[4][4];
    #pragma unroll
    for (int i = 0; i < 4; i++)
        #pragma unroll
        for (int j = 0; j < 4; j++) acc[i][j] = (f32x4){0.f, 0.f, 0.f, 0.f};

    const int srow = tid >> 3;         // 0..31
    const int scol = (tid & 7) * 8;    // 0..56

    for (int kt = 0; kt < K; kt += 64) {
        #pragma unroll
        for (int p = 0; p < 4; p++) {
            int r = p * 32 + srow;
            *(uint4*)(&As[r * LDT + scol]) = *(const uint4*)(&A[(size_t)(m0 + r) * K + kt + scol]);
            *(uint4*)(&Bs[r * LDT + scol]) = *(const uint4*)(&Bt[(size_t)(n0 + r) * K + kt + scol]);
        }
        __syncthreads();
        #pragma unroll
        for (int k0 = 0; k0 < 64; k0 += 32) {
            bf16x8 a[4], b[4];
            #pragma unroll
            for (int i = 0; i < 4; i++)
                a[i] = *(const bf16x8*)(&As[(wr + i * 16 + ln) * LDT + k0 + quad * 8]);
            #pragma unroll
            for (int j = 0; j < 4; j++)
                b[j] = *(const bf16x8*)(&Bs[(wc + j * 16 + ln) * LDT + k0 + quad * 8]);
            #pragma unroll
            for (int i = 0; i < 4; i++)
                #pragma unroll
                for (int j = 0; j < 4; j++)
                    acc[i][j] = __builtin_amdgcn_mfma_f32_16x16x32_bf16(a[i], b[j], acc[i][j], 0, 0, 0);
        }
        __syncthreads();
    }
    #pragma unroll
    for (int i = 0; i < 4; i++)
        #pragma unroll
        for (int r = 0; r < 4; r++) {
            int row = m0 + wr + i * 16 + quad * 4 + r;
            #pragma unroll
            for (int j = 0; j < 4; j++) {
                int col = n0 + wc + j * 16 + ln;
                float v = acc[i][j][r];
                if (OUT_BF16) ((u16*)C)[(size_t)row * N + col] = f2bf(v);
                else          ((float*)C)[(size_t)row * N + col] = v;
            }
        }
}

// ---------------- RoPE in-place on bf16 (B,T,H,64); q also gets *0.125 score scale ----------
__global__ void rope_kernel(u16* __restrict__ data, int rows, int nheads, float scale) {
    const int ppr = nheads * 32;  // pairs per row
    const int total = rows * ppr;
    for (int p = blockIdx.x * blockDim.x + threadIdx.x; p < total;
         p += gridDim.x * blockDim.x) {
        int row = p / ppr;
        int pr = p - row * ppr;
        int h = pr >> 5;
        int i = pr & 31;
        int t = row & 2047;  // row = b*T + t, T = 2048
        float freq = powf(10000.f, -(float)(2 * i) / 64.f);
        float ang = (float)t * freq;
        float s, c;
        sincosf(ang, &s, &c);
        size_t base = (size_t)row * (nheads * 64) + h * 64 + 2 * i;
        float xe = bf2f(data[base]), xo = bf2f(data[base + 1]);
        data[base]     = f2bf((xe * c - xo * s) * scale);
        data[base + 1] = f2bf((xe * s + xo * c) * scale);
    }
}

// ---------------- flash attention ----------------
// grid: (T/128, B*NH). block 256. Q tile 128x64 resident; iterate 128-wide K/V tiles.
__global__ __launch_bounds__(256) void attn_kernel(const u16* __restrict__ qb,
                                                   const u16* __restrict__ kb,
                                                   const u16* __restrict__ vb,
                                                   u16* __restrict__ ob) {
    const int T = 2048, HD = 64, NH = 32;
    const int CQ = NH * HD;   // 2048
    const int CKV = 8 * HD;   // 512
    __shared__ __align__(16) u16 Qs[128 * LDT];
    __shared__ __align__(16) u16 Ks[128 * LDT];
    __shared__ __align__(16) u16 Vt[64 * 136];    // V^T: [d][s]
    __shared__ __align__(16) u16 Ps[128 * 136];   // P: [t][s]
    __shared__ float m_s[128], l_s[128], alpha_s[128];
    __shared__ float red[2][128];

    const int tid = threadIdx.x;
    const int bh = blockIdx.y;
    const int b = bh >> 5, h = bh & 31, kvh = h >> 2;
    const int t0 = blockIdx.x * 128;
    const u16* qbase = qb + ((size_t)(b * T + t0) * CQ + h * HD);
    const u16* kbase = kb + ((size_t)(b * T) * CKV + kvh * HD);
    const u16* vbase = vb + ((size_t)(b * T) * CKV + kvh * HD);

    const int w = tid >> 6, lane = tid & 63, quad = lane >> 4, ln = lane & 15;
    const int wr = (w >> 1) * 64, wc = (w & 1) * 64;
    const int srow = tid >> 3, scol = (tid & 7) * 8;

    // stage Q once
    #pragma unroll
    for (int p = 0; p < 4; p++) {
        int r = p * 32 + srow;
        *(uint4*)(&Qs[r * LDT + scol]) = *(const uint4*)(&qbase[(size_t)r * CQ + scol]);
    }
    if (tid < 128) { m_s[tid] = -1e30f; l_s[tid] = 0.f; }

    f32x4 o_acc[2][4];
    #pragma unroll
    for (int i = 0; i < 2; i++)
        #pragma unroll
        for (int j = 0; j < 4; j++) o_acc[i][j] = (f32x4){0.f, 0.f, 0.f, 0.f};

    for (int st = 0; st < T; st += 128) {
        // stage K tile and transposed V tile
        #pragma unroll
        for (int p = 0; p < 4; p++) {
            int r = p * 32 + srow;
            *(uint4*)(&Ks[r * LDT + scol]) = *(const uint4*)(&kbase[(size_t)(st + r) * CKV + scol]);
            uint4 vv = *(const uint4*)(&vbase[(size_t)(st + r) * CKV + scol]);
            u16* pv = (u16*)&vv;
            #pragma unroll
            for (int e = 0; e < 8; e++) Vt[(scol + e) * 136 + r] = pv[e];
        }
        __syncthreads();

        // S = Q K^T (scaled already): each wave 64x64
        f32x4 s_acc[4][4];
        #pragma unroll
        for (int i = 0; i < 4; i++)
            #pragma unroll
            for (int j = 0; j < 4; j++) s_acc[i][j] = (f32x4){0.f, 0.f, 0.f, 0.f};
        #pragma unroll
        for (int k0 = 0; k0 < 64; k0 += 32) {
            bf16x8 a[4], bf[4];
            #pragma unroll
            for (int i = 0; i < 4; i++)
                a[i] = *(const bf16x8*)(&Qs[(wr + i * 16 + ln) * LDT + k0 + quad * 8]);
            #pragma unroll
            for (int j = 0; j < 4; j++)
                bf[j] = *(const bf16x8*)(&Ks[(wc + j * 16 + ln) * LDT + k0 + quad * 8]);
            #pragma unroll
            for (int i = 0; i < 4; i++)
                #pragma unroll
                for (int j = 0; j < 4; j++)
                    s_acc[i][j] = __builtin_amdgcn_mfma_f32_16x16x32_bf16(a[i], bf[j], s_acc[i][j], 0, 0, 0);
        }

        // per-row max over this wave's 64 cols
        #pragma unroll
        for (int i = 0; i < 4; i++)
            #pragma unroll
            for (int r = 0; r < 4; r++) {
                float mx = fmaxf(fmaxf(s_acc[i][0][r], s_acc[i][1][r]),
                                 fmaxf(s_acc[i][2][r], s_acc[i][3][r]));
                #pragma unroll
                for (int d = 1; d < 16; d <<= 1) mx = fmaxf(mx, __shfl_xor(mx, d, 64));
                if (ln == 0) red[w & 1][wr + i * 16 + quad * 4 + r] = mx;
            }
        __syncthreads();

        if (tid < 128) {
            float mo = m_s[tid];
            float mn = fmaxf(mo, fmaxf(red[0][tid], red[1][tid]));
            float a = __expf(mo - mn);
            m_s[tid] = mn; alpha_s[tid] = a; l_s[tid] *= a;
        }
        __syncthreads();

        // P = exp(S - m) -> bf16 to LDS; partial row sums; rescale O by alpha
        #pragma unroll
        for (int i = 0; i < 4; i++)
            #pragma unroll
            for (int r = 0; r < 4; r++) {
                int row = wr + i * 16 + quad * 4 + r;
                float mrow = m_s[row];
                float rs = 0.f;
                #pragma unroll
                for (int j = 0; j < 4; j++) {
                    float pv = __expf(s_acc[i][j][r] - mrow);
                    rs += pv;
                    Ps[row * 136 + wc + j * 16 + ln] = f2bf(pv);
                }
                #pragma unroll
                for (int d = 1; d < 16; d <<= 1) rs += __shfl_xor(rs, d, 64);
                if (ln == 0) red[w & 1][row] = rs;
            }
        #pragma unroll
        for (int i = 0; i < 2; i++)
            #pragma unroll
            for (int r = 0; r < 4; r++) {
                float a = alpha_s[w * 32 + i * 16 + quad * 4 + r];
                #pragma unroll
                for (int j = 0; j < 4; j++) o_acc[i][j][r] *= a;
            }
        __syncthreads();

        if (tid < 128) l_s[tid] += red[0][tid] + red[1][tid];

        // O += P V : each wave rows [w*32, w*32+32), all 64 d-cols
        #pragma unroll
        for (int k0 = 0; k0 < 128; k0 += 32) {
            bf16x8 a[2], bf[4];
            #pragma unroll
            for (int i = 0; i < 2; i++)
                a[i] = *(const bf16x8*)(&Ps[(w * 32 + i * 16 + ln) * 136 + k0 + quad * 8]);
            #pragma unroll
            for (int j = 0; j < 4; j++)
                bf[j] = *(const bf16x8*)(&Vt[(j * 16 + ln) * 136 + k0 + quad * 8]);
            #pragma unroll
            for (int i = 0; i < 2; i++)
                #pragma unroll
                for (int j = 0; j < 4; j++)
                    o_acc[i][j] = __builtin_amdgcn_mfma_f32_16x16x32_bf16(a[i], bf[j], o_acc[i][j], 0, 0, 0);
        }
        __syncthreads();
    }

    // epilogue: O / l -> bf16
    #pragma unroll
    for (int i = 0; i < 2; i++)
        #pragma unroll
        for (int r = 0; r < 4; r++) {
            int row = w * 32 + i * 16 + quad * 4 + r;
            float linv = 1.f / l_s[row];
            #pragma unroll
            for (int j = 0; j < 4; j++) {
                int col = j * 16 + ln;
                ob[(size_t)(b * T + t0 + row) * CQ + h * HD + col] = f2bf(o_acc[i][j][r] * linv);
            }
        }
}

// ---------------- workspace layout (bytes) ----------------
#define WS_X_BF   ((size_t)0)            // 4096*2048*2 = 16777216
#define WS_WQT    ((size_t)16777216)     // 2048*2048*2 =  8388608
#define WS_WKT    ((size_t)25165824)     //  512*2048*2 =  2097152
#define WS_WVT    ((size_t)27262976)     //  512*2048*2 =  2097152
#define WS_WOT    ((size_t)29360128)     // 2048*2048*2 =  8388608
#define WS_QBF    ((size_t)37748736)     // 4096*2048*2 = 16777216
#define WS_KBF    ((size_t)54525952)     // 4096*512*2  =  4194304
#define WS_VBF    ((size_t)58720256)     // 4096*512*2  =  4194304
#define WS_ABF    ((size_t)62914560)     // 4096*2048*2 = 16777216
// total 79691776 bytes (~76 MB)

extern "C" void kernel_launch(void* const* d_in, const int* in_sizes, int n_in,
                              void* d_out, int out_size, void* d_ws, size_t ws_size,
                              hipStream_t stream) {
    const float* x  = (const float*)d_in[0];
    const float* wq = (const float*)d_in[1];
    const float* wk = (const float*)d_in[2];
    const float* wv = (const float*)d_in[3];
    const float* wo = (const float*)d_in[4];
    char* ws = (char*)d_ws;
    u16* xbf  = (u16*)(ws + WS_X_BF);
    u16* wqT  = (u16*)(ws + WS_WQT);
    u16* wkT  = (u16*)(ws + WS_WKT);
    u16* wvT  = (u16*)(ws + WS_WVT);
    u16* woT  = (u16*)(ws + WS_WOT);
    u16* qbf  = (u16*)(ws + WS_QBF);
    u16* kbf  = (u16*)(ws + WS_KBF);
    u16* vbf  = (u16*)(ws + WS_VBF);
    u16* abf  = (u16*)(ws + WS_ABF);
    float* out = (float*)d_out;

    // casts / transposes
    cast_bf16_kernel<<<2048, 256, 0, stream>>>(x, xbf, (size_t)4096 * 2048 / 4);
    transpose_cast_kernel<<<dim3(64, 64), dim3(32, 8), 0, stream>>>(wq, wqT, 2048, 2048);
    transpose_cast_kernel<<<dim3(16, 64), dim3(32, 8), 0, stream>>>(wk, wkT, 2048, 512);
    transpose_cast_kernel<<<dim3(16, 64), dim3(32, 8), 0, stream>>>(wv, wvT, 2048, 512);
    transpose_cast_kernel<<<dim3(64, 64), dim3(32, 8), 0, stream>>>(wo, woT, 2048, 2048);

    // projections
    gemm_bt_kernel<1><<<dim3(16, 32), 256, 0, stream>>>(xbf, wqT, qbf, 4096, 2048, 2048);
    gemm_bt_kernel<1><<<dim3(4, 32),  256, 0, stream>>>(xbf, wkT, kbf, 4096, 512, 2048);
    gemm_bt_kernel<1><<<dim3(4, 32),  256, 0, stream>>>(xbf, wvT, vbf, 4096, 512, 2048);

    // RoPE (q also gets 1/sqrt(64) folded in)
    rope_kernel<<<8192, 256, 0, stream>>>(qbf, 4096, 32, 0.125f);
    rope_kernel<<<2048, 256, 0, stream>>>(kbf, 4096, 8, 1.0f);

    // attention
    attn_kernel<<<dim3(16, 64), 256, 0, stream>>>(qbf, kbf, vbf, abf);

    // output projection -> fp32 d_out
    gemm_bt_kernel<0><<<dim3(16, 32), 256, 0, stream>>>(abf, woT, out, 4096, 2048, 2048);
}